// Round 10
// baseline (70.740 us; speedup 1.0000x reference)
//
#include <hip/hip_runtime.h>

// Problem shape (fixed by reference setup_inputs):
//   bert_emb:    [B=4, Lp=256, D=768] fp32
//   pieces2word: [B=4, Lw=200, Lp=256] int32 (0/1)
//   out:         [B=4, Lw=200, D=768] fp32
// out[b,w,d] = max over {p : mask[b,w,p]!=0} of emb[b,p,d], else global min(emb).
//
// R9 design — R6 structure (W=5, 960x512, proven 30 waves/CU) plus:
//  (a) max3 pair-merge: acc = fmaxf(acc, fmaxf(b0?v0:-inf, b1?v1:-inf))
//      -> 4 cndmask + 2 v_max3 per 2 pieces per float2 = 1.5 VALU ops/elem
//      (R6 was 2.0) -> merge floor 4.0 -> 3.0 us.
//  (b) XCD-clustered mapping: blockIdx = wg*24 + (b*CHUNKS+chunk). 24 % 8
//      == 0, so all 40 blocks of one (b,chunk) stream hit the SAME XCD
//      under round-robin dispatch -> each stream HBM-fetched ~once
//      (FETCH ~12.4 MB -> ~4 MB), higher L2 hit. Heuristic only; mapping
//      changes affect speed, never correctness.
//  - acc init = -inf is bit-exact (max is a selection). Empty-mask word
//    (P ~ 2^-256, never for fixed inputs) -> correct global-min fallback.

#define B_  4
#define LP_ 256
#define LW_ 200
#define D_  768
#define D2_ (D_ / 2)              // 384 float2 per row
#define CHUNKS 6                  // 6 chunks x 128 floats (1 float2 per lane)
#define W_  5                     // words per block
#define WG_ (LW_ / W_)            // 40 word-groups
#define NSTREAM (B_ * CHUNKS)     // 24 (b,chunk) streams
#define NBLK (NSTREAM * WG_)      // 960 blocks
#define SEGS 8                    // waves (piece segments) per block
#define PPS 32                    // pieces per segment

__global__ __launch_bounds__(512) void word_max_scan(
    const float* __restrict__ emb, const int* __restrict__ p2w,
    float* __restrict__ out)
{
    const int blk   = blockIdx.x;
    const int sid   = blk % NSTREAM;   // stream id: constant mod 8 -> one XCD
    const int wg    = blk / NSTREAM;
    const int chunk = sid % CHUNKS;
    const int b     = sid / CHUNKS;
    const int lane  = threadIdx.x & 63;
    const int s     = threadIdx.x >> 6;     // piece segment 0..7
    const int w0    = wg * W_;

    // Each wave ballots a 32-bit mask for its 32 pieces, per word.
    unsigned int m[W_];
    const int pc = s * PPS + (lane & 31);
    #pragma unroll
    for (int j = 0; j < W_; ++j) {
        const int* mrow = p2w + (b * LW_ + w0 + j) * LP_;
        m[j] = (unsigned int)__ballot((lane < 32) && (mrow[pc] != 0));
    }

    const float ninf = __uint_as_float(0xFF800000u);
    float2 acc[W_];
    #pragma unroll
    for (int j = 0; j < W_; ++j) acc[j] = make_float2(ninf, ninf);

    // Wave's row stream: rows [32s, 32s+32), column = chunk*64 + lane (float2).
    const float2* rps = (const float2*)(emb + (size_t)b * LP_ * D_)
                        + chunk * 64 + lane + (size_t)(s * PPS) * D2_;

    #pragma unroll
    for (int g = 0; g < PPS; g += 8) {
        float2 v[8];
        #pragma unroll
        for (int k = 0; k < 8; ++k)
            v[k] = rps[(size_t)(g + k) * D2_];
        #pragma unroll
        for (int k = 0; k < 8; k += 2) {
            #pragma unroll
            for (int j = 0; j < W_; ++j) {
                const bool b0 = (m[j] >> (g + k + 0)) & 1u;
                const bool b1 = (m[j] >> (g + k + 1)) & 1u;
                const float s0x = b0 ? v[k + 0].x : ninf;
                const float s1x = b1 ? v[k + 1].x : ninf;
                const float s0y = b0 ? v[k + 0].y : ninf;
                const float s1y = b1 ? v[k + 1].y : ninf;
                acc[j].x = fmaxf(acc[j].x, fmaxf(s0x, s1x));  // v_max3
                acc[j].y = fmaxf(acc[j].y, fmaxf(s0y, s1y));  // v_max3
            }
        }
    }

    // Merge the 8 segments via LDS (20.5 KB).
    __shared__ float2 sacc[SEGS][W_][64];
    __shared__ unsigned int smask[SEGS][W_];
    #pragma unroll
    for (int j = 0; j < W_; ++j) sacc[s][j][lane] = acc[j];
    if (lane == 0) {
        #pragma unroll
        for (int j = 0; j < W_; ++j) smask[s][j] = m[j];
    }
    __syncthreads();

    // Wave j (< W_) finalizes word j.
    if (s < W_) {
        const int j = s;
        float2 r = sacc[0][j][lane];
        #pragma unroll
        for (int seg = 1; seg < SEGS; ++seg) {
            r.x = fmaxf(r.x, sacc[seg][j][lane].x);
            r.y = fmaxf(r.y, sacc[seg][j][lane].y);
        }
        unsigned int om = 0;
        #pragma unroll
        for (int seg = 0; seg < SEGS; ++seg) om |= smask[seg][j];

        if (om == 0u) {
            // Never taken for the fixed inputs; correct fallback = global
            // min over ALL of emb (reference min_value semantics).
            const float4* x = (const float4*)emb;
            const int n4 = (B_ * LP_ * D_) / 4;
            float mn = __uint_as_float(0x7F800000u);  // +inf
            for (int i = lane; i < n4; i += 64) {
                float4 vv = x[i];
                mn = fminf(mn, fminf(fminf(vv.x, vv.y), fminf(vv.z, vv.w)));
            }
            #pragma unroll
            for (int off = 32; off > 0; off >>= 1)
                mn = fminf(mn, __shfl_down(mn, off, 64));
            mn = __shfl(mn, 0, 64);
            r = make_float2(mn, mn);
        }

        float2* op = (float2*)out + (size_t)(b * LW_ + w0 + j) * D2_
                     + chunk * 64 + lane;
        *op = r;
    }
}

extern "C" void kernel_launch(void* const* d_in, const int* in_sizes, int n_in,
                              void* d_out, int out_size, void* d_ws, size_t ws_size,
                              hipStream_t stream) {
    const float* emb = (const float*)d_in[0];
    const int*   p2w = (const int*)d_in[1];
    float*       out = (float*)d_out;
    (void)d_ws; (void)ws_size;

    word_max_scan<<<NBLK, 512, 0, stream>>>(emb, p2w, out);
}

// Round 11
// 66.899 us; speedup vs baseline: 1.0574x; 1.0574x over previous
//
#include <hip/hip_runtime.h>

// Problem shape (fixed by reference setup_inputs):
//   bert_emb:    [B=4, Lp=256, D=768] fp32
//   pieces2word: [B=4, Lw=200, Lp=256] int32 (0/1)
//   out:         [B=4, Lw=200, D=768] fp32
// out[b,w,d] = max over {p : mask[b,w,p]!=0} of emb[b,p,d], else global min(emb).
//
// R10 — REVERT to R6 (best: 67.3 us total, kernel ~10.5 us by R7's
// double-launch measurement). R8 (W=10), R9 (max3 + XCD swizzle) both
// regressed; this restores the proven configuration.
//
// R6 design — branchless piece-scan, 8-way piece-split:
//  - ONE kernel, no workspace. 960 blocks x 512 threads (8 waves):
//    block = (b, chunk of 128 floats, group of W=5 words).
//    Wave s (0..7) owns pieces [32s, 32s+32): ballots its own 5x32-bit
//    word-masks from p2w, streams its 32 emb row-chunks once (unroll-8
//    dwordx2 loads), merges into 5 float2 accumulators branchlessly:
//       acc.x = fmaxf(acc.x, bit ? v.x : -inf)   // v_cndmask + v_max
//    30 waves/CU (7.5/SIMD).
//  - End: LDS merge of 8 segments (20.5 KB), float2 stores.
//  - acc init = -inf is bit-exact (max is a selection; min_value never wins
//    when any piece is active). Empty-mask word (P ~ 2^-256, never for the
//    fixed inputs) -> correct global-min fallback, never taken.

#define B_  4
#define LP_ 256
#define LW_ 200
#define D_  768
#define D2_ (D_ / 2)              // 384 float2 per row
#define CHUNKS 6                  // 6 chunks x 128 floats (1 float2 per lane)
#define W_  5                     // words per block
#define WG_ (LW_ / W_)            // 40 word-groups
#define NBLK (B_ * CHUNKS * WG_)  // 960 blocks
#define SEGS 8                    // waves (piece segments) per block
#define PPS 32                    // pieces per segment

__global__ __launch_bounds__(512) void word_max_scan(
    const float* __restrict__ emb, const int* __restrict__ p2w,
    float* __restrict__ out)
{
    const int blk   = blockIdx.x;
    const int wg    = blk % WG_;
    const int rest  = blk / WG_;
    const int chunk = rest % CHUNKS;
    const int b     = rest / CHUNKS;
    const int lane  = threadIdx.x & 63;
    const int s     = threadIdx.x >> 6;     // piece segment 0..7
    const int w0    = wg * W_;

    // Each wave ballots a 32-bit mask for its 32 pieces, per word.
    unsigned int m[W_];
    const int pc = s * PPS + (lane & 31);
    #pragma unroll
    for (int j = 0; j < W_; ++j) {
        const int* mrow = p2w + (b * LW_ + w0 + j) * LP_;
        m[j] = (unsigned int)__ballot((lane < 32) && (mrow[pc] != 0));
    }

    const float ninf = __uint_as_float(0xFF800000u);
    float2 acc[W_];
    #pragma unroll
    for (int j = 0; j < W_; ++j) acc[j] = make_float2(ninf, ninf);

    // Wave's row stream: rows [32s, 32s+32), column = chunk*64 + lane (float2).
    const float2* rps = (const float2*)(emb + (size_t)b * LP_ * D_)
                        + chunk * 64 + lane + (size_t)(s * PPS) * D2_;

    #pragma unroll
    for (int g = 0; g < PPS; g += 8) {
        float2 v[8];
        #pragma unroll
        for (int k = 0; k < 8; ++k)
            v[k] = rps[(size_t)(g + k) * D2_];
        #pragma unroll
        for (int k = 0; k < 8; ++k) {
            #pragma unroll
            for (int j = 0; j < W_; ++j) {
                const bool bit = (m[j] >> (g + k)) & 1u;  // immediate shift
                acc[j].x = fmaxf(acc[j].x, bit ? v[k].x : ninf);
                acc[j].y = fmaxf(acc[j].y, bit ? v[k].y : ninf);
            }
        }
    }

    // Merge the 8 segments via LDS.
    __shared__ float2 sacc[SEGS][W_][64];
    __shared__ unsigned int smask[SEGS][W_];
    #pragma unroll
    for (int j = 0; j < W_; ++j) sacc[s][j][lane] = acc[j];
    if (lane == 0) {
        #pragma unroll
        for (int j = 0; j < W_; ++j) smask[s][j] = m[j];
    }
    __syncthreads();

    // Wave j (< W_) finalizes word j.
    if (s < W_) {
        const int j = s;
        float2 r = sacc[0][j][lane];
        #pragma unroll
        for (int seg = 1; seg < SEGS; ++seg) {
            r.x = fmaxf(r.x, sacc[seg][j][lane].x);
            r.y = fmaxf(r.y, sacc[seg][j][lane].y);
        }
        unsigned int om = 0;
        #pragma unroll
        for (int seg = 0; seg < SEGS; ++seg) om |= smask[seg][j];

        if (om == 0u) {
            // Never taken for the fixed inputs; correct fallback = global
            // min over ALL of emb (reference min_value semantics).
            const float4* x = (const float4*)emb;
            const int n4 = (B_ * LP_ * D_) / 4;
            float mn = __uint_as_float(0x7F800000u);  // +inf
            for (int i = lane; i < n4; i += 64) {
                float4 vv = x[i];
                mn = fminf(mn, fminf(fminf(vv.x, vv.y), fminf(vv.z, vv.w)));
            }
            #pragma unroll
            for (int off = 32; off > 0; off >>= 1)
                mn = fminf(mn, __shfl_down(mn, off, 64));
            mn = __shfl(mn, 0, 64);
            r = make_float2(mn, mn);
        }

        float2* op = (float2*)out + (size_t)(b * LW_ + w0 + j) * D2_
                     + chunk * 64 + lane;
        *op = r;
    }
}

extern "C" void kernel_launch(void* const* d_in, const int* in_sizes, int n_in,
                              void* d_out, int out_size, void* d_ws, size_t ws_size,
                              hipStream_t stream) {
    const float* emb = (const float*)d_in[0];
    const int*   p2w = (const int*)d_in[1];
    float*       out = (float*)d_out;
    (void)d_ws; (void)ws_size;

    word_max_scan<<<NBLK, 512, 0, stream>>>(emb, p2w, out);
}